// Round 11
// baseline (18627.846 us; speedup 1.0000x reference)
//
#include <hip/hip_runtime.h>

#define SEQ   1024
#define TLEN  1024
#define NTHR  512
#define NBLK  256
#define SLICE 3072

// d_out float map (786,432 floats total):
//  [0,131072)        h0T[2][128][512]   (parity, unit, merged-batch)  -- L3-coherent via atomics
//  [131072,262144)   h1T[2][128][512]
//  floats [266240,266752): 8 barrier counters, 256B apart (memset 0 every call)
//  slices 96..223 @ offset [1024,1536): final-h stash (floats >= 295936, disjoint)
#define H1BASE 131072
#define CNTF   266240

__device__ __forceinline__ float sig1(float x)  { return 1.0f / (1.0f + __expf(-x)); }
__device__ __forceinline__ float tanh1(float x) { return 1.0f - 2.0f / (__expf(2.0f * x) + 1.0f); }

// L3-coherent h access: write-through stores, cache-bypassing loads (no fences needed).
__device__ __forceinline__ void astore(float* p, float v) {
  __hip_atomic_store(p, v, __ATOMIC_RELAXED, __HIP_MEMORY_SCOPE_AGENT);
}
__device__ __forceinline__ float aload(const float* p) {
  return __hip_atomic_load(p, __ATOMIC_RELAXED, __HIP_MEMORY_SCOPE_AGENT);
}

struct LP {
  const float *X1, *X2, *W1m, *b1m, *bih0, *bhh0, *bih1, *bhh1;
  const float *Wih0, *Whh0, *Wih1, *Whh1;
  float* out; unsigned* cnt;
};

// bg-local barrier: 32 blocks per domain, one padded counter each, single-counter poll.
__device__ __forceinline__ void gridbar(unsigned* cnt, unsigned phase, int slot) {
  __syncthreads();
  if (threadIdx.x == 0) {
    unsigned* c = cnt + slot * 64;
    __hip_atomic_fetch_add(c, 1u, __ATOMIC_RELAXED, __HIP_MEMORY_SCOPE_AGENT);
    const unsigned tgt = (phase + 1u) * 32u;
    while (__hip_atomic_load(c, __ATOMIC_RELAXED, __HIP_MEMORY_SCOPE_AGENT) < tgt)
      __builtin_amdgcn_s_sleep(2);
  }
  __syncthreads();
}

// 4 consecutive unit-rows (k0..k0+3) of global h [unit][512] for batch eb.
__device__ __forceinline__ float4 ald4(const float* s, int k0, int eb) {
  return make_float4(aload(&s[(k0 + 0) * 512 + eb]), aload(&s[(k0 + 1) * 512 + eb]),
                     aload(&s[(k0 + 2) * 512 + eb]), aload(&s[(k0 + 3) * 512 + eb]));
}

// K-length 4-gate dot: h from swizzled LDS row, weights = uniform-address global
// streams (L1$-resident, one 16B request per wave per load). K multiple of 4.
template <int K>
__device__ __forceinline__ void dotK(const float* hrow, int swz,
                                     const float* w0, const float* w1,
                                     const float* w2, const float* w3,
                                     float acc[4]) {
  #pragma unroll 4
  for (int kq = 0; kq < K; kq += 4) {
    float4 hv = *(const float4*)&hrow[kq ^ swz];
    float4 a = *(const float4*)&w0[kq];
    float4 b = *(const float4*)&w1[kq];
    float4 c = *(const float4*)&w2[kq];
    float4 d = *(const float4*)&w3[kq];
    acc[0] = fmaf(a.x, hv.x, fmaf(a.y, hv.y, fmaf(a.z, hv.z, fmaf(a.w, hv.w, acc[0]))));
    acc[1] = fmaf(b.x, hv.x, fmaf(b.y, hv.y, fmaf(b.z, hv.z, fmaf(b.w, hv.w, acc[1]))));
    acc[2] = fmaf(c.x, hv.x, fmaf(c.y, hv.y, fmaf(c.z, hv.z, fmaf(c.w, hv.w, acc[2]))));
    acc[3] = fmaf(d.x, hv.x, fmaf(d.y, hv.y, fmaf(d.z, hv.z, fmaf(d.w, hv.w, acc[3]))));
  }
}

extern "C" __global__ void __launch_bounds__(NTHR)
lstm_gs(LP p) {
  __shared__ float sm[16384];            // 64 KiB: L1 blk: h0[64][128]|h1[64][128]; L0: feat[64][64]|h0[64][128]
  const int tid = threadIdx.x;
  const int bid = blockIdx.x;
  const bool L1r = (bid >= 128);
  const int lb = L1r ? bid - 128 : bid;
  const int bg = lb & 7, ug = lb >> 3;   // batch-group (sync domain), unit-group
  const int uu = tid >> 6, bl = tid & 63;
  const int u  = ug * 8 + uu;            // owned hidden unit
  const int eb = bg * 64 + bl;           // merged batch 0..511
  const int swz = (bl & 15) << 2;

  float* out = p.out;
  float* h0w = out;
  float* h1w = out + H1BASE;

  // Domain-local zeroing of the parity-1 buffers (each domain zeroes ONLY its own
  // bg columns -> no cross-domain init dependency). L0 blocks: 16*512 = 8192 thr
  // cover 128 rows x 64 cols, one float per buffer each.
  if (!L1r) {
    const int z = ug * 512 + tid;        // 0..8191
    const int row = z >> 6, col = bg * 64 + (z & 63);
    astore(&out[65536 + row * 512 + col],  0.0f);  // h0T[1]
    astore(&out[196608 + row * 512 + col], 0.0f);  // h1T[1]
  }

  float bias[4];
  {
    const float* bi = L1r ? p.bih1 : p.bih0;
    const float* bh = L1r ? p.bhh1 : p.bhh0;
    #pragma unroll
    for (int g = 0; g < 4; ++g) bias[g] = bi[g * 128 + u] + bh[g * 128 + u];
  }

  // Wave-uniform weight row pointers (read from ORIGINAL tensors every step;
  // per-CU working set 32KB = L1$-resident after first step).
  const float *wr0, *wr1, *wr2, *wr3, *vr0, *vr1, *vr2, *vr3;
  if (!L1r) {
    wr0 = p.Wih0 + (0 * 128 + u) * 64;  wr1 = p.Wih0 + (1 * 128 + u) * 64;
    wr2 = p.Wih0 + (2 * 128 + u) * 64;  wr3 = p.Wih0 + (3 * 128 + u) * 64;
    vr0 = p.Whh0 + (0 * 128 + u) * 128; vr1 = p.Whh0 + (1 * 128 + u) * 128;
    vr2 = p.Whh0 + (2 * 128 + u) * 128; vr3 = p.Whh0 + (3 * 128 + u) * 128;
  } else {
    wr0 = p.Wih1 + (0 * 128 + u) * 128; wr1 = p.Wih1 + (1 * 128 + u) * 128;
    wr2 = p.Wih1 + (2 * 128 + u) * 128; wr3 = p.Wih1 + (3 * 128 + u) * 128;
    vr0 = p.Whh1 + (0 * 128 + u) * 128; vr1 = p.Whh1 + (1 * 128 + u) * 128;
    vr2 = p.Whh1 + (2 * 128 + u) * 128; vr3 = p.Whh1 + (3 * 128 + u) * 128;
  }

  gridbar(p.cnt, 0, bg);                 // domain zeros visible

  float c_reg = 0.0f;

  for (int j = 0; j <= SEQ; ++j) {
    const bool act = L1r ? (j >= 1) : (j < SEQ);

    // ---- stage: issue ALL h loads into registers, then write tiles ----
    if (act) {
      if (!L1r) {
        // mlp1 feat for own batch (m = uu*8..+8)
        const float* X = (eb < 256) ? p.X1 + ((size_t)eb * SEQ + j) * 5
                                    : p.X2 + ((size_t)(eb - 256) * SEQ + j) * 5;
        float x0 = X[0], x1 = X[1], x2 = X[2], x3 = X[3], x4 = X[4];
        const float* s0 = h0w + ((j + 1) & 1) * 65536;   // h0[t-1]
        float4 ph0 = ald4(s0, uu * 16 + 0,  eb);
        float4 ph1 = ald4(s0, uu * 16 + 4,  eb);
        float4 ph2 = ald4(s0, uu * 16 + 8,  eb);
        float4 ph3 = ald4(s0, uu * 16 + 12, eb);
        float fv[8];
        #pragma unroll
        for (int jj = 0; jj < 8; ++jj) {
          const float* w = p.W1m + (uu * 8 + jj) * 5;
          float s = p.b1m[uu * 8 + jj];
          s = fmaf(x0, w[0], s); s = fmaf(x1, w[1], s); s = fmaf(x2, w[2], s);
          s = fmaf(x3, w[3], s); s = fmaf(x4, w[4], s);
          fv[jj] = fmaxf(s, 0.0f);
        }
        const int k0 = uu * 8;
        *(float4*)&sm[bl * 64 + (k0 ^ swz)]       = make_float4(fv[0], fv[1], fv[2], fv[3]);
        *(float4*)&sm[bl * 64 + ((k0 + 4) ^ swz)] = make_float4(fv[4], fv[5], fv[6], fv[7]);
        float* hT = sm + 4096 + bl * 128;
        *(float4*)&hT[(uu * 16 + 0)  ^ swz] = ph0;
        *(float4*)&hT[(uu * 16 + 4)  ^ swz] = ph1;
        *(float4*)&hT[(uu * 16 + 8)  ^ swz] = ph2;
        *(float4*)&hT[(uu * 16 + 12) ^ swz] = ph3;
      } else {
        const float* s0 = h0w + ((j + 1) & 1) * 65536;   // h0[t] (t=j-1)
        const float* s1 = h1w + (j & 1) * 65536;         // h1[t-1]
        float4 p00 = ald4(s0, uu * 16 + 0,  eb);
        float4 p01 = ald4(s0, uu * 16 + 4,  eb);
        float4 p02 = ald4(s0, uu * 16 + 8,  eb);
        float4 p03 = ald4(s0, uu * 16 + 12, eb);
        float4 p10 = ald4(s1, uu * 16 + 0,  eb);
        float4 p11 = ald4(s1, uu * 16 + 4,  eb);
        float4 p12 = ald4(s1, uu * 16 + 8,  eb);
        float4 p13 = ald4(s1, uu * 16 + 12, eb);
        float* hA = sm + bl * 128;
        float* hB = sm + 8192 + bl * 128;
        *(float4*)&hA[(uu * 16 + 0)  ^ swz] = p00;
        *(float4*)&hA[(uu * 16 + 4)  ^ swz] = p01;
        *(float4*)&hA[(uu * 16 + 8)  ^ swz] = p02;
        *(float4*)&hA[(uu * 16 + 12) ^ swz] = p03;
        *(float4*)&hB[(uu * 16 + 0)  ^ swz] = p10;
        *(float4*)&hB[(uu * 16 + 4)  ^ swz] = p11;
        *(float4*)&hB[(uu * 16 + 8)  ^ swz] = p12;
        *(float4*)&hB[(uu * 16 + 12) ^ swz] = p13;
      }
    }
    __syncthreads();

    // ---- compute full K + state update ----
    if (act) {
      float acc[4] = {bias[0], bias[1], bias[2], bias[3]};
      if (!L1r) {
        dotK<64>(sm + bl * 64, swz, wr0, wr1, wr2, wr3, acc);          // Wih0 . feat
        dotK<128>(sm + 4096 + bl * 128, swz, vr0, vr1, vr2, vr3, acc); // Whh0 . h0[t-1]
      } else {
        dotK<128>(sm + bl * 128, swz, wr0, wr1, wr2, wr3, acc);        // Wih1 . h0[t]
        dotK<128>(sm + 8192 + bl * 128, swz, vr0, vr1, vr2, vr3, acc); // Whh1 . h1[t-1]
      }
      float gi = sig1(acc[0]), gf = sig1(acc[1]);
      float gg = tanh1(acc[2]), go = sig1(acc[3]);
      c_reg = gf * c_reg + gi * gg;
      float hv = go * tanh1(c_reg);
      if (!L1r) {
        astore(&h0w[(j & 1) * 65536 + u * 512 + eb], hv);
      } else {
        astore(&h1w[((j + 1) & 1) * 65536 + u * 512 + eb], hv);
        if (j == SEQ)
          out[(size_t)(96 + (eb >> 2)) * SLICE + 1024 + (eb & 3) * 128 + u] = hv;
      }
    }
    gridbar(p.cnt, j + 1, bg);
  }
}

// base[b][m] = b1[m] + W1[m,0:128].hL[b] + W1[m,128:256].hR[b] -> out[b*SLICE + m]
extern "C" __global__ void __launch_bounds__(128)
mlp2_pre(const float* __restrict__ W1, const float* __restrict__ b1, float* out) {
  __shared__ float inpS[256];
  const int b = blockIdx.x, tid = threadIdx.x;
  inpS[tid]       = out[(size_t)(96  + (b >> 2)) * SLICE + 1024 + (b & 3) * 128 + tid];
  inpS[128 + tid] = out[(size_t)(160 + (b >> 2)) * SLICE + 1024 + (b & 3) * 128 + tid];
  __syncthreads();
  const float* wr = W1 + (size_t)tid * 257;
  float s = b1[tid];
  #pragma unroll 4
  for (int k = 0; k < 256; ++k) s = fmaf(wr[k], inpS[k], s);
  out[(size_t)b * SLICE + tid] = s;
}

// out[b][t][o] = b2[o] + sum_m W2[o][m] * relu(base[b][m] + W1[m][256]*T[b][t])
extern "C" __global__ void __launch_bounds__(256)
mlp2_k(const float* __restrict__ T, const float* __restrict__ W1,
       const float* __restrict__ b2, const float* __restrict__ W2, float* out) {
  __shared__ float baseS[128], w1l[128], w2S[384];
  const int b = blockIdx.x, tid = threadIdx.x;
  if (tid < 128) {
    baseS[tid] = out[(size_t)b * SLICE + tid];   // read own slice BEFORE any write
    w1l[tid]   = W1[(size_t)tid * 257 + 256];
  }
  w2S[tid] = W2[tid];                            // 256 threads fill all 384
  if (tid < 128) w2S[256 + tid] = W2[256 + tid];
  __syncthreads();
  float x[4];
  #pragma unroll
  for (int q = 0; q < 4; ++q) x[q] = T[(size_t)b * TLEN + tid + q * 256];
  float a0[4], a1[4], a2[4];
  #pragma unroll
  for (int q = 0; q < 4; ++q) { a0[q] = b2[0]; a1[q] = b2[1]; a2[q] = b2[2]; }
  for (int mm = 0; mm < 128; ++mm) {
    float bm = baseS[mm], wl = w1l[mm];
    float w20 = w2S[mm], w21 = w2S[128 + mm], w22 = w2S[256 + mm];
    #pragma unroll
    for (int q = 0; q < 4; ++q) {
      float hv = fmaxf(fmaf(wl, x[q], bm), 0.0f);
      a0[q] = fmaf(w20, hv, a0[q]);
      a1[q] = fmaf(w21, hv, a1[q]);
      a2[q] = fmaf(w22, hv, a2[q]);
    }
  }
  #pragma unroll
  for (int q = 0; q < 4; ++q) {
    float* o = out + ((size_t)b * TLEN + tid + q * 256) * 3;
    o[0] = a0[q]; o[1] = a1[q]; o[2] = a2[q];
  }
}

extern "C" void kernel_launch(void* const* d_in, const int* in_sizes, int n_in,
                              void* d_out, int out_size, void* d_ws, size_t ws_size,
                              hipStream_t stream) {
  (void)in_sizes; (void)n_in; (void)out_size; (void)d_ws; (void)ws_size;
  const float* X1   = (const float*)d_in[0];
  const float* X2   = (const float*)d_in[1];
  const float* T    = (const float*)d_in[2];
  const float* W1m  = (const float*)d_in[3];
  const float* b1m  = (const float*)d_in[4];
  const float* Wih0 = (const float*)d_in[5];
  const float* Whh0 = (const float*)d_in[6];
  const float* bih0 = (const float*)d_in[7];
  const float* bhh0 = (const float*)d_in[8];
  const float* Wih1 = (const float*)d_in[9];
  const float* Whh1 = (const float*)d_in[10];
  const float* bih1 = (const float*)d_in[11];
  const float* bhh1 = (const float*)d_in[12];
  const float* W1p  = (const float*)d_in[13];
  const float* b1p  = (const float*)d_in[14];
  const float* W2p  = (const float*)d_in[15];
  const float* b2p  = (const float*)d_in[16];

  float* out = (float*)d_out;
  unsigned* cnt = (unsigned*)((char*)d_out + (size_t)CNTF * 4);

  // 8 domain counters must start at 0 every call
  hipMemsetAsync(cnt, 0, 2048, stream);

  LP hp{X1, X2, W1m, b1m, bih0, bhh0, bih1, bhh1, Wih0, Whh0, Wih1, Whh1, out, cnt};
  void* args[] = {(void*)&hp};
  hipLaunchCooperativeKernel((const void*)lstm_gs, dim3(NBLK), dim3(NTHR),
                             args, 0, stream);

  mlp2_pre<<<dim3(256), dim3(128), 0, stream>>>(W1p, b1p, out);
  mlp2_k<<<dim3(256), dim3(256), 0, stream>>>(T, W1p, b2p, W2p, out);
}

// Round 12
// 7534.723 us; speedup vs baseline: 2.4723x; 2.4723x over previous
//
#include <hip/hip_runtime.h>

#define SEQ   1024
#define TLEN  1024
#define NB_B  4
#define NTHR  512
#define SLICE 3072

// d_out float map (786,432 floats):
//  [0,229376)       transposed weights (prep_t), consumed during lstm
//  [229376,294912)  h0 ring slot0 [128 pairs][512]   (< stash start 295936)
//  [688128,753664)  h0 ring slot1                    (> stash end 686592)
//  [753664,770048)  flags: flag0[p] @ +p*64, flag1[p] @ +8192+p*64 (memset 0)
//  slices 96..223 @ offset [1024,1536): final-h stash
#define WT0IH 0
#define WT0HH 32768
#define WT1IH 98304
#define WT1HH 163840
#define WTOT  229376
#define RING0 229376
#define RING1 688128
#define FLAGF 753664

__device__ __forceinline__ float sig1(float x)  { return 1.0f / (1.0f + __expf(-x)); }
__device__ __forceinline__ float tanh1(float x) { return 1.0f - 2.0f / (__expf(2.0f * x) + 1.0f); }

__device__ __forceinline__ void astoref(float* pp, float v) {
  __hip_atomic_store(pp, v, __ATOMIC_RELAXED, __HIP_MEMORY_SCOPE_AGENT);
}
__device__ __forceinline__ float aloadf(const float* pp) {
  return __hip_atomic_load(pp, __ATOMIC_RELAXED, __HIP_MEMORY_SCOPE_AGENT);
}
__device__ __forceinline__ void astoreu(unsigned* pp, unsigned v) {
  __hip_atomic_store(pp, v, __ATOMIC_RELAXED, __HIP_MEMORY_SCOPE_AGENT);
}
__device__ __forceinline__ unsigned aloadu(const unsigned* pp) {
  return __hip_atomic_load(pp, __ATOMIC_RELAXED, __HIP_MEMORY_SCOPE_AGENT);
}

// One-time weight transpose: [row][k] -> [k>>2][row][k&3], into d_out[0..WTOT)
extern "C" __global__ void __launch_bounds__(256)
prep_t(const float* __restrict__ Wih0, const float* __restrict__ Whh0,
       const float* __restrict__ Wih1, const float* __restrict__ Whh1,
       float* __restrict__ wt) {
  const int idx = blockIdx.x * 256 + threadIdx.x;
  if (idx >= WTOT) return;
  float v; int r, k, base;
  if (idx < 32768)      { r = idx >> 6;  k = idx & 63;                  v = Wih0[idx]; base = WT0IH; }
  else if (idx < 98304) { int j = idx - 32768;  r = j >> 7; k = j & 127; v = Whh0[j];  base = WT0HH; }
  else if (idx < 163840){ int j = idx - 98304;  r = j >> 7; k = j & 127; v = Wih1[j];  base = WT1IH; }
  else                  { int j = idx - 163840; r = j >> 7; k = j & 127; v = Whh1[j];  base = WT1HH; }
  wt[base + (((k >> 2) * 512 + r) << 2) + (k & 3)] = v;
}

// Paired pipeline: blocks 0..127 = layer0 for batches 4p..4p+3 (all units, local
// recurrence); blocks 128..255 = layer1 for the same batches, one step behind.
// Cross-block traffic: 512-float h0 publish + 2 flags per pair per step.
extern "C" __global__ void __launch_bounds__(NTHR)
lstm_pair(const float* __restrict__ X1, const float* __restrict__ X2,
          const float* __restrict__ W1m, const float* __restrict__ b1m,
          const float* __restrict__ bih0, const float* __restrict__ bhh0,
          const float* __restrict__ bih1, const float* __restrict__ bhh1,
          const float* wt, float* out) {
  __shared__ float hbuf[NB_B * 320];   // per batch: feat[64] | h0[128] | h1[128]
  __shared__ float gacc[512 * NB_B];   // [gate-row][batch]
  __shared__ float xS[NB_B * 5];

  const int tid = threadIdx.x;
  const int bid = blockIdx.x;
  const bool L1role = bid >= 128;
  const int p  = L1role ? bid - 128 : bid;
  const int r  = tid;                  // gate row 0..511
  const int u  = tid & 127;            // hidden unit
  const int bp = tid >> 7;             // batch slot 0..3

  unsigned* flag0 = (unsigned*)(out + FLAGF) + p * 64;
  unsigned* flag1 = (unsigned*)(out + FLAGF) + 8192 + p * 64;

  for (int i = tid; i < NB_B * 320; i += NTHR) hbuf[i] = 0.0f;
  __syncthreads();

  if (!L1role) {
    // ---------------- layer-0 producer ----------------
    const int m  = tid & 63;           // mlp1 unit
    const int bf = tid >> 6;           // mlp1 batch slot (active if < NB_B)
    float w1r[5];
    #pragma unroll
    for (int i = 0; i < 5; ++i) w1r[i] = W1m[m * 5 + i];
    const float b1r   = b1m[m];
    const float bias0 = bih0[r] + bhh0[r];

    const int b5 = (tid < NB_B * 5) ? tid / 5 : 0;
    const int c5 = tid - b5 * 5;
    const int ebx = p * NB_B + b5;
    const float* xsrc = (ebx < 256) ? (X1 + (size_t)ebx * SEQ * 5 + c5)
                                    : (X2 + (size_t)(ebx - 256) * SEQ * 5 + c5);

    const float4* wih0 = (const float4*)(wt + WT0IH) + r;  // [kc][512] float4s
    const float4* whh0 = (const float4*)(wt + WT0HH) + r;

    float c0 = 0.0f;
    for (int t = 0; t < SEQ; ++t) {
      if (tid < NB_B * 5) xS[tid] = xsrc[(size_t)t * 5];
      __syncthreads();

      if (bf < NB_B) {                 // mlp1 feat
        const float* xb = &xS[bf * 5];
        float s = b1r;
        #pragma unroll
        for (int i = 0; i < 5; ++i) s = fmaf(w1r[i], xb[i], s);
        hbuf[bf * 320 + m] = fmaxf(s, 0.0f);
      }
      // ack-wait for ring slot t&1 (L1 must have staged h0[t-2]); overlaps feat
      if (tid == 0 && t >= 2) {
        while (aloadu(flag1) < (unsigned)(t - 1)) __builtin_amdgcn_s_sleep(2);
      }
      __syncthreads();

      {  // layer0 gate rows: Wih0.feat + Whh0.h0[t-1]   (r6-proven)
        float acc[NB_B];
        #pragma unroll
        for (int b = 0; b < NB_B; ++b) acc[b] = bias0;
        #pragma unroll 4
        for (int kc = 0; kc < 16; ++kc) {
          float4 wv = wih0[kc * 512];
          #pragma unroll
          for (int b = 0; b < NB_B; ++b) {
            float4 hv = *(const float4*)&hbuf[b * 320 + kc * 4];
            acc[b] = fmaf(wv.x, hv.x, fmaf(wv.y, hv.y,
                     fmaf(wv.z, hv.z, fmaf(wv.w, hv.w, acc[b]))));
          }
        }
        #pragma unroll 4
        for (int kc = 0; kc < 32; ++kc) {
          float4 wv = whh0[kc * 512];
          #pragma unroll
          for (int b = 0; b < NB_B; ++b) {
            float4 hv = *(const float4*)&hbuf[b * 320 + 64 + kc * 4];
            acc[b] = fmaf(wv.x, hv.x, fmaf(wv.y, hv.y,
                     fmaf(wv.z, hv.z, fmaf(wv.w, hv.w, acc[b]))));
          }
        }
        *(float4*)&gacc[r * NB_B] = make_float4(acc[0], acc[1], acc[2], acc[3]);
      }
      __syncthreads();

      float hv;
      {  // state update -> h0[t]
        float gi = gacc[(u)       * NB_B + bp];
        float gf = gacc[(128 + u) * NB_B + bp];
        float gg = gacc[(256 + u) * NB_B + bp];
        float go = gacc[(384 + u) * NB_B + bp];
        float cc = sig1(gf) * c0 + sig1(gi) * tanh1(gg);
        c0 = cc;
        hv = sig1(go) * tanh1(cc);
        hbuf[bp * 320 + 64 + u] = hv;
      }
      __syncthreads();

      // publish h0[t] (coalesced: idx = tid) then signal
      float* rg = out + ((t & 1) ? RING1 : RING0) + p * 512;
      astoref(&rg[tid], hv);
      __syncthreads();                 // all waves' stores drained (vmcnt0)
      if (tid == 0) astoreu(flag0, (unsigned)(t + 1));
    }
  } else {
    // ---------------- layer-1 consumer ----------------
    const float bias1 = bih1[r] + bhh1[r];
    const float4* wih1 = (const float4*)(wt + WT1IH) + r;
    const float4* whh1 = (const float4*)(wt + WT1HH) + r;

    float c1 = 0.0f;
    for (int s = 0; s < SEQ; ++s) {
      if (tid == 0) {
        while (aloadu(flag0) < (unsigned)(s + 1)) __builtin_amdgcn_s_sleep(2);
      }
      __syncthreads();

      // stage h0[s]: one coalesced aload per thread -> LDS
      const float* rg = out + ((s & 1) ? RING1 : RING0) + p * 512;
      hbuf[bp * 320 + 64 + u] = aloadf(&rg[tid]);
      __syncthreads();
      if (tid == 0) astoreu(flag1, (unsigned)(s + 1));   // slot consumed

      {  // layer1 gate rows: Wih1.h0[s] + Whh1.h1[s-1]   (r6-proven)
        float acc[NB_B];
        #pragma unroll
        for (int b = 0; b < NB_B; ++b) acc[b] = bias1;
        #pragma unroll 4
        for (int kc = 0; kc < 32; ++kc) {
          float4 wv = wih1[kc * 512];
          #pragma unroll
          for (int b = 0; b < NB_B; ++b) {
            float4 hv = *(const float4*)&hbuf[b * 320 + 64 + kc * 4];
            acc[b] = fmaf(wv.x, hv.x, fmaf(wv.y, hv.y,
                     fmaf(wv.z, hv.z, fmaf(wv.w, hv.w, acc[b]))));
          }
        }
        #pragma unroll 4
        for (int kc = 0; kc < 32; ++kc) {
          float4 wv = whh1[kc * 512];
          #pragma unroll
          for (int b = 0; b < NB_B; ++b) {
            float4 hv = *(const float4*)&hbuf[b * 320 + 192 + kc * 4];
            acc[b] = fmaf(wv.x, hv.x, fmaf(wv.y, hv.y,
                     fmaf(wv.z, hv.z, fmaf(wv.w, hv.w, acc[b]))));
          }
        }
        *(float4*)&gacc[r * NB_B] = make_float4(acc[0], acc[1], acc[2], acc[3]);
      }
      __syncthreads();

      {  // state update -> h1[s]; final stash
        float gi = gacc[(u)       * NB_B + bp];
        float gf = gacc[(128 + u) * NB_B + bp];
        float gg = gacc[(256 + u) * NB_B + bp];
        float go = gacc[(384 + u) * NB_B + bp];
        float cc = sig1(gf) * c1 + sig1(gi) * tanh1(gg);
        c1 = cc;
        float hvv = sig1(go) * tanh1(cc);
        hbuf[bp * 320 + 192 + u] = hvv;
        if (s == SEQ - 1)
          out[(size_t)(96 + p) * SLICE + 1024 + bp * 128 + u] = hvv;
      }
      __syncthreads();
    }
  }
}

// base[b][m] = b1[m] + W1[m,0:128].hL[b] + W1[m,128:256].hR[b] -> out[b*SLICE + m]
extern "C" __global__ void __launch_bounds__(128)
mlp2_pre(const float* __restrict__ W1, const float* __restrict__ b1, float* out) {
  __shared__ float inpS[256];
  const int b = blockIdx.x, tid = threadIdx.x;
  inpS[tid]       = out[(size_t)(96  + (b >> 2)) * SLICE + 1024 + (b & 3) * 128 + tid];
  inpS[128 + tid] = out[(size_t)(160 + (b >> 2)) * SLICE + 1024 + (b & 3) * 128 + tid];
  __syncthreads();
  const float* wr = W1 + (size_t)tid * 257;
  float s = b1[tid];
  #pragma unroll 4
  for (int k = 0; k < 256; ++k) s = fmaf(wr[k], inpS[k], s);
  out[(size_t)b * SLICE + tid] = s;
}

// out[b][t][o] = b2[o] + sum_m W2[o][m] * relu(base[b][m] + W1[m][256]*T[b][t])
extern "C" __global__ void __launch_bounds__(256)
mlp2_k(const float* __restrict__ T, const float* __restrict__ W1,
       const float* __restrict__ b2, const float* __restrict__ W2, float* out) {
  __shared__ float baseS[128], w1l[128], w2S[384];
  const int b = blockIdx.x, tid = threadIdx.x;
  if (tid < 128) {
    baseS[tid] = out[(size_t)b * SLICE + tid];   // read own slice BEFORE any write
    w1l[tid]   = W1[(size_t)tid * 257 + 256];
  }
  w2S[tid] = W2[tid];                            // 256 threads fill all 384
  if (tid < 128) w2S[256 + tid] = W2[256 + tid];
  __syncthreads();
  float x[4];
  #pragma unroll
  for (int q = 0; q < 4; ++q) x[q] = T[(size_t)b * TLEN + tid + q * 256];
  float a0[4], a1[4], a2[4];
  #pragma unroll
  for (int q = 0; q < 4; ++q) { a0[q] = b2[0]; a1[q] = b2[1]; a2[q] = b2[2]; }
  for (int mm = 0; mm < 128; ++mm) {
    float bm = baseS[mm], wl = w1l[mm];
    float w20 = w2S[mm], w21 = w2S[128 + mm], w22 = w2S[256 + mm];
    #pragma unroll
    for (int q = 0; q < 4; ++q) {
      float hv = fmaxf(fmaf(wl, x[q], bm), 0.0f);
      a0[q] = fmaf(w20, hv, a0[q]);
      a1[q] = fmaf(w21, hv, a1[q]);
      a2[q] = fmaf(w22, hv, a2[q]);
    }
  }
  #pragma unroll
  for (int q = 0; q < 4; ++q) {
    float* o = out + ((size_t)b * TLEN + tid + q * 256) * 3;
    o[0] = a0[q]; o[1] = a1[q]; o[2] = a2[q];
  }
}

extern "C" void kernel_launch(void* const* d_in, const int* in_sizes, int n_in,
                              void* d_out, int out_size, void* d_ws, size_t ws_size,
                              hipStream_t stream) {
  (void)in_sizes; (void)n_in; (void)out_size; (void)d_ws; (void)ws_size;
  const float* X1   = (const float*)d_in[0];
  const float* X2   = (const float*)d_in[1];
  const float* T    = (const float*)d_in[2];
  const float* W1m  = (const float*)d_in[3];
  const float* b1m  = (const float*)d_in[4];
  const float* Wih0 = (const float*)d_in[5];
  const float* Whh0 = (const float*)d_in[6];
  const float* bih0 = (const float*)d_in[7];
  const float* bhh0 = (const float*)d_in[8];
  const float* Wih1 = (const float*)d_in[9];
  const float* Whh1 = (const float*)d_in[10];
  const float* bih1 = (const float*)d_in[11];
  const float* bhh1 = (const float*)d_in[12];
  const float* W1p  = (const float*)d_in[13];
  const float* b1p  = (const float*)d_in[14];
  const float* W2p  = (const float*)d_in[15];
  const float* b2p  = (const float*)d_in[16];

  float* out = (float*)d_out;

  // flags must start at 0 every call
  hipMemsetAsync((char*)d_out + (size_t)FLAGF * 4, 0, 65536, stream);

  prep_t<<<dim3(896), dim3(256), 0, stream>>>(Wih0, Whh0, Wih1, Whh1, out);
  lstm_pair<<<dim3(256), dim3(NTHR), 0, stream>>>(X1, X2, W1m, b1m,
                                                  bih0, bhh0, bih1, bhh1, out, out);
  mlp2_pre<<<dim3(256), dim3(128), 0, stream>>>(W1p, b1p, out);
  mlp2_k<<<dim3(256), dim3(256), 0, stream>>>(T, W1p, b2p, W2p, out);
}